// Round 1
// baseline (1456.649 us; speedup 1.0000x reference)
//
#include <hip/hip_runtime.h>
#include <hip/hip_bf16.h>

// ISTA persistent-LDS kernel.
// Rows of d are independent across the whole iteration loop; each block owns
// R_ROWS rows and iterates numIter times entirely out of LDS/registers.
// S (iteration-invariant) is cached in VGPRs: worker (jg,ks) holds
// S[jg*4..jg*4+3][ks*20..ks*20+19] (80 regs). d is read as broadcast float4
// from LDS (1 ds_read_b128 per 16 FMAs). k is split 5 ways; a combine phase
// sums partials + Wy and applies the soft threshold.

#define N_DIM     100
#define M_DIM     70
#define R_ROWS    4
#define NTHREADS  128
#define JGROUPS   25   // column groups
#define JT        4    // columns per worker
#define KSPLIT    5    // k-range splits
#define KLEN      20   // k per worker
#define PART_PITCH 104 // padded j-pitch for partials

__global__ __launch_bounds__(NTHREADS, 2)
void ista_persistent(const float* __restrict__ y,
                     const float* __restrict__ S,
                     const float* __restrict__ W,
                     const float* __restrict__ thr,
                     const int*   __restrict__ numIter,
                     float* __restrict__ out)
{
    __shared__ float d_lds[2][R_ROWS][N_DIM];             // double-buffered d tile
    __shared__ float part[KSPLIT][R_ROWS][PART_PITCH];    // k-split partial sums
    __shared__ float wy[R_ROWS][N_DIM];                   // Wy tile (constant)

    const int t    = threadIdx.x;
    const int row0 = blockIdx.x * R_ROWS;
    const float th = thr[0];
    const int iters = numIter[0];

    const int jg = t / KSPLIT;        // 0..24 for workers
    const int ks = t - jg * KSPLIT;   // 0..4
    const bool worker = (t < JGROUPS * KSPLIT);   // 125 of 128 threads

    // ---- one-time: load S fragment into registers (static indices only) ----
    float sreg[JT][KLEN];
    if (worker) {
        #pragma unroll
        for (int jj = 0; jj < JT; ++jj) {
            const float* srow = S + (jg * JT + jj) * N_DIM + ks * KLEN;
            #pragma unroll
            for (int kk = 0; kk < KLEN; ++kk) sreg[jj][kk] = srow[kk];
        }
    }

    // ---- one-time: Wy = y @ W.T for this block's rows; zero d ----
    if (t < N_DIM) {
        const float* wrow = W + t * M_DIM;   // W is [N][M] row-major; (y@W.T)[r][j]=sum_m y[r][m]*W[j][m]
        for (int r = 0; r < R_ROWS; ++r) {
            const float* yrow = y + (size_t)(row0 + r) * M_DIM;
            float acc = 0.f;
            #pragma unroll 10
            for (int mm = 0; mm < M_DIM; ++mm) acc = fmaf(yrow[mm], wrow[mm], acc);
            wy[r][t] = acc;
            d_lds[0][r][t] = 0.f;
        }
    }
    __syncthreads();

    int buf = 0;
    for (int it = 0; it < iters; ++it) {
        // ---- FMA phase: partial[ks][r][j] = sum_{k in ks-range} S[j][k]*d[r][k] ----
        if (worker) {
            #pragma unroll
            for (int r = 0; r < R_ROWS; ++r) {
                float acc[JT];
                #pragma unroll
                for (int jj = 0; jj < JT; ++jj) acc[jj] = 0.f;
                const float* drow = &d_lds[buf][r][ks * KLEN];
                #pragma unroll
                for (int kc = 0; kc < KLEN / 4; ++kc) {
                    const float4 dv = *(const float4*)(drow + kc * 4);  // broadcast b128, conflict-free
                    const float dq0 = dv.x, dq1 = dv.y, dq2 = dv.z, dq3 = dv.w;
                    #pragma unroll
                    for (int jj = 0; jj < JT; ++jj) {
                        acc[jj] = fmaf(sreg[jj][kc*4+0], dq0, acc[jj]);
                        acc[jj] = fmaf(sreg[jj][kc*4+1], dq1, acc[jj]);
                        acc[jj] = fmaf(sreg[jj][kc*4+2], dq2, acc[jj]);
                        acc[jj] = fmaf(sreg[jj][kc*4+3], dq3, acc[jj]);
                    }
                }
                *(float4*)&part[ks][r][jg * JT] =
                    make_float4(acc[0], acc[1], acc[2], acc[3]);
            }
        }
        __syncthreads();

        // ---- combine phase: sum partials + Wy, soft-threshold, write next d ----
        if (t < N_DIM) {
            #pragma unroll
            for (int r = 0; r < R_ROWS; ++r) {
                float s = wy[r][t];
                #pragma unroll
                for (int p = 0; p < KSPLIT; ++p) s += part[p][r][t];
                // soft_thr(x) = relu(x-th) - relu(-x-th) = sign(x)*max(|x|-th,0)
                float mag = fabsf(s) - th;
                mag = mag > 0.f ? mag : 0.f;
                d_lds[buf ^ 1][r][t] = (s >= 0.f) ? mag : -mag;
            }
        }
        __syncthreads();
        buf ^= 1;
    }

    // ---- write result ----
    if (t < N_DIM) {
        for (int r = 0; r < R_ROWS; ++r)
            out[(size_t)(row0 + r) * N_DIM + t] = d_lds[buf][r][t];
    }
}

extern "C" void kernel_launch(void* const* d_in, const int* in_sizes, int n_in,
                              void* d_out, int out_size, void* d_ws, size_t ws_size,
                              hipStream_t stream) {
    const float* y       = (const float*)d_in[0];
    const float* S       = (const float*)d_in[1];
    const float* W       = (const float*)d_in[2];
    const float* thr     = (const float*)d_in[3];
    const int*   numIter = (const int*)d_in[4];
    float* out = (float*)d_out;

    const int Brows = in_sizes[0] / M_DIM;   // 4096
    const int nblk  = Brows / R_ROWS;        // 1024 blocks
    ista_persistent<<<nblk, NTHREADS, 0, stream>>>(y, S, W, thr, numIter, out);
}

// Round 2
// 1230.466 us; speedup vs baseline: 1.1838x; 1.1838x over previous
//
#include <hip/hip_runtime.h>
#include <hip/hip_bf16.h>

// ISTA persistent-LDS kernel, round 2.
// Rows of d are independent across the whole iteration loop; each block owns
// R_ROWS rows and iterates numIter times entirely out of LDS/registers.
// S (iteration-invariant) is cached in VGPRs: worker (jg,ks) holds
// S[jg*4..jg*4+3][ks*20..ks*20+19] (80 regs).
//
// Round-2 changes vs round 1:
//  - part[] is written LANE-LINEAR (part[r][t*4], float4) -> conflict-free by
//    construction (round 1 wrote part[ks][r][jg*4]; ks-stride 416 dwords is
//    0 mod 32 -> bank 4*(jg%8) -> ~10-way conflict, 2.5e8 conflict cycles).
//    Combine gathers part[r][(jg*5+ks)*4+jj]: per-ks bank map (20*jg+jj)%32,
//    only jg vs jg+8 alias -> 2-way = free (m136).
//  - R_ROWS 4 -> 2: grid 1024 -> 2048 blocks = 8 blocks/CU, 16 waves/CU, so
//    independent blocks hide each other's barriers/LDS latency.

#define N_DIM     100
#define M_DIM     70
#define R_ROWS    2
#define NTHREADS  128
#define JGROUPS   25   // column groups
#define JT        4    // columns per worker
#define KSPLIT    5    // k-range splits
#define KLEN      20   // k per worker
#define NWORK     (JGROUPS * KSPLIT)   // 125 workers

__global__ __launch_bounds__(NTHREADS)
void ista_persistent(const float* __restrict__ y,
                     const float* __restrict__ S,
                     const float* __restrict__ W,
                     const float* __restrict__ thr,
                     const int*   __restrict__ numIter,
                     float* __restrict__ out)
{
    __shared__ float d_lds[2][R_ROWS][N_DIM];      // double-buffered d tile
    __shared__ float part[R_ROWS][NTHREADS * JT];  // lane-linear partials
    __shared__ float wy[R_ROWS][N_DIM];            // Wy tile (constant)

    const int t    = threadIdx.x;
    const int row0 = blockIdx.x * R_ROWS;
    const float th = thr[0];
    const int iters = numIter[0];

    const int jg = t / KSPLIT;        // 0..24 for workers
    const int ks = t - jg * KSPLIT;   // 0..4
    const bool worker = (t < NWORK);  // 125 of 128 threads

    // ---- one-time: load S fragment into registers (static indices only) ----
    float sreg[JT][KLEN];
    if (worker) {
        #pragma unroll
        for (int jj = 0; jj < JT; ++jj) {
            const float* srow = S + (jg * JT + jj) * N_DIM + ks * KLEN;
            #pragma unroll
            for (int kk = 0; kk < KLEN; ++kk) sreg[jj][kk] = srow[kk];
        }
    }

    // ---- one-time: Wy = y @ W.T for this block's rows; zero d ----
    if (t < N_DIM) {
        const float* wrow = W + t * M_DIM;   // (y@W.T)[r][j] = sum_m y[r][m]*W[j][m]
        for (int r = 0; r < R_ROWS; ++r) {
            const float* yrow = y + (size_t)(row0 + r) * M_DIM;
            float acc = 0.f;
            #pragma unroll 10
            for (int mm = 0; mm < M_DIM; ++mm) acc = fmaf(yrow[mm], wrow[mm], acc);
            wy[r][t] = acc;
            d_lds[0][r][t] = 0.f;
        }
    }
    __syncthreads();

    int buf = 0;
    for (int it = 0; it < iters; ++it) {
        // ---- FMA phase: partials over this worker's k-slice ----
        if (worker) {
            #pragma unroll
            for (int r = 0; r < R_ROWS; ++r) {
                float acc[JT];
                #pragma unroll
                for (int jj = 0; jj < JT; ++jj) acc[jj] = 0.f;
                const float* drow = &d_lds[buf][r][ks * KLEN];
                #pragma unroll
                for (int kc = 0; kc < KLEN / 4; ++kc) {
                    // broadcast b128: banks {0,20,8,28,16}+4kc, disjoint -> conflict-free
                    const float4 dv = *(const float4*)(drow + kc * 4);
                    const float dq0 = dv.x, dq1 = dv.y, dq2 = dv.z, dq3 = dv.w;
                    #pragma unroll
                    for (int jj = 0; jj < JT; ++jj) {
                        acc[jj] = fmaf(sreg[jj][kc*4+0], dq0, acc[jj]);
                        acc[jj] = fmaf(sreg[jj][kc*4+1], dq1, acc[jj]);
                        acc[jj] = fmaf(sreg[jj][kc*4+2], dq2, acc[jj]);
                        acc[jj] = fmaf(sreg[jj][kc*4+3], dq3, acc[jj]);
                    }
                }
                // lane-linear float4 write: conflict-free by construction
                *(float4*)&part[r][t * JT] =
                    make_float4(acc[0], acc[1], acc[2], acc[3]);
            }
        }
        __syncthreads();

        // ---- combine phase: gather 5 partials + Wy, soft-threshold, write next d ----
        if (t < N_DIM) {
            const int cjg = t >> 2;        // column group of column t
            const int cjj = t & 3;         // column-in-group
            #pragma unroll
            for (int r = 0; r < R_ROWS; ++r) {
                float s = wy[r][t];
                #pragma unroll
                for (int p = 0; p < KSPLIT; ++p)
                    s += part[r][(cjg * KSPLIT + p) * JT + cjj];  // 2-way bank alias = free
                // soft_thr(x) = sign(x)*max(|x|-th,0)
                float mag = fabsf(s) - th;
                mag = mag > 0.f ? mag : 0.f;
                d_lds[buf ^ 1][r][t] = (s >= 0.f) ? mag : -mag;
            }
        }
        __syncthreads();
        buf ^= 1;
    }

    // ---- write result ----
    if (t < N_DIM) {
        for (int r = 0; r < R_ROWS; ++r)
            out[(size_t)(row0 + r) * N_DIM + t] = d_lds[buf][r][t];
    }
}

extern "C" void kernel_launch(void* const* d_in, const int* in_sizes, int n_in,
                              void* d_out, int out_size, void* d_ws, size_t ws_size,
                              hipStream_t stream) {
    const float* y       = (const float*)d_in[0];
    const float* S       = (const float*)d_in[1];
    const float* W       = (const float*)d_in[2];
    const float* thr     = (const float*)d_in[3];
    const int*   numIter = (const int*)d_in[4];
    float* out = (float*)d_out;

    const int Brows = in_sizes[0] / M_DIM;   // 4096
    const int nblk  = Brows / R_ROWS;        // 2048 blocks
    ista_persistent<<<nblk, NTHREADS, 0, stream>>>(y, S, W, thr, numIter, out);
}

// Round 3
// 666.158 us; speedup vs baseline: 2.1866x; 1.8471x over previous
//
#include <hip/hip_runtime.h>
#include <hip/hip_bf16.h>

// ISTA via split-bf16 MFMA, round 3.
// d_new[16 x 100] = softthr(d @ S^T + Wy): A = d (M=16 rows, K=100->128),
// B^T = S (row-major [N][K], N=100->128). Split S = S_hi + S_lo, d = d_hi + d_lo
// (bf16 RNE hi, bf16 residual lo); compute S_hi*d_hi + S_hi*d_lo + S_lo*d_hi
// (~2^-17 rel err/iter; accumulated << 0.15 threshold).
//
// grid=256 (16 rows/CU exact), block=256 = 4 waves, 2 N-tiles/wave.
// S frags register-resident (iteration-invariant); Wy precomputed into
// C-layout regs and used as MFMA C-seed. d_hi/d_lo double-buffered in LDS,
// XOR-swizzled (byte ^= (row&7)<<4) so the 256B row stride spreads banks.
// ONE barrier/iter: reads hit buf[cur], writes hit buf[cur^1].
//
// Layout safety: A and B frags both loaded contiguous-8-in-k from k-major
// storage; per-lane-group k-permutation cancels (kappa_A == kappa_B, as in the
// ref-checked m92/m97 GEMMs). C/D layout = m89-verified (col=lane&15,
// row=(lane>>4)*4+reg).

#define ROWS     16
#define KPAD     128
#define N_DIM    100
#define M_DIM    70
#define NTHREADS 256

typedef __attribute__((ext_vector_type(8))) short short8;
typedef __attribute__((ext_vector_type(4))) float f32x4;

static __device__ __forceinline__ unsigned short f2bf(float f) {
    unsigned u = __float_as_uint(f);
    u += 0x7FFF + ((u >> 16) & 1);          // RNE
    return (unsigned short)(u >> 16);
}
static __device__ __forceinline__ float bf2f(unsigned short b) {
    return __uint_as_float(((unsigned)b) << 16);
}

__global__ __launch_bounds__(NTHREADS)
void ista_mfma(const float* __restrict__ y,
               const float* __restrict__ S,
               const float* __restrict__ W,
               const float* __restrict__ thr,
               const int*   __restrict__ numIter,
               float* __restrict__ out)
{
    __shared__ __align__(16) unsigned short dh[2][ROWS * KPAD];  // d hi (bf16 bits)
    __shared__ __align__(16) unsigned short dl[2][ROWS * KPAD];  // d lo (bf16 bits)

    const int t    = threadIdx.x;
    const int wv   = t >> 6;        // wave 0..3
    const int l    = t & 63;
    const int l15  = l & 15;
    const int lg   = l >> 4;        // lane group 0..3
    const int row0 = blockIdx.x * ROWS;
    const float th  = thr[0];
    const int iters = numIter[0];

    // ---- one-time: S fragments (B operand, [N][K] row-major), split hi/lo ----
    short8 Bh[2][4], Bl[2][4];
    #pragma unroll
    for (int n2 = 0; n2 < 2; ++n2) {
        const int j = (wv * 2 + n2) * 16 + l15;          // output column
        #pragma unroll
        for (int kt = 0; kt < 4; ++kt) {
            #pragma unroll
            for (int i = 0; i < 8; ++i) {
                const int k = kt * 32 + lg * 8 + i;
                const float v = (j < N_DIM && k < N_DIM) ? S[j * N_DIM + k] : 0.f;
                const unsigned short hb = f2bf(v);
                Bh[n2][kt][i] = (short)hb;
                Bl[n2][kt][i] = (short)f2bf(v - bf2f(hb));
            }
        }
    }

    // ---- one-time: Wy in C layout (seed for MFMA accumulator) ----
    f32x4 Wyr[2];
    #pragma unroll
    for (int n2 = 0; n2 < 2; ++n2) {
        const int col = (wv * 2 + n2) * 16 + l15;
        #pragma unroll
        for (int q = 0; q < 4; ++q) {
            const int row = lg * 4 + q;
            float acc = 0.f;
            if (col < N_DIM) {
                const float* yr = y + (size_t)(row0 + row) * M_DIM;
                const float* wr = W + (size_t)col * M_DIM;
                #pragma unroll 10
                for (int m = 0; m < M_DIM; ++m) acc = fmaf(yr[m], wr[m], acc);
            }
            Wyr[n2][q] = acc;
        }
    }

    // ---- zero buffer 0 (cols >= 100 stay 0 forever: S,Wy pads are 0) ----
    for (int idx = t; idx < ROWS * KPAD; idx += NTHREADS) {
        dh[0][idx] = 0; dl[0][idx] = 0;
    }
    __syncthreads();

    int cur = 0;
    for (int it = 0; it < iters; ++it) {
        // ---- A fragments of d_hi/d_lo from LDS (swizzled, 16B aligned) ----
        short8 Ah[4], Al[4];
        #pragma unroll
        for (int kt = 0; kt < 4; ++kt) {
            const unsigned off =
                (unsigned)((l15 * KPAD + kt * 32 + lg * 8) * 2) ^ (unsigned)((l15 & 7) << 4);
            Ah[kt] = *(const short8*)((const char*)dh[cur] + off);
            Al[kt] = *(const short8*)((const char*)dl[cur] + off);
        }

        // ---- 24 MFMAs: 3 precision products x 4 K-tiles x 2 N-tiles ----
        f32x4 C0 = Wyr[0], C1 = Wyr[1];
        #pragma unroll
        for (int kt = 0; kt < 4; ++kt) {
            C0 = __builtin_amdgcn_mfma_f32_16x16x32_bf16(Ah[kt], Bh[0][kt], C0, 0, 0, 0);
            C1 = __builtin_amdgcn_mfma_f32_16x16x32_bf16(Ah[kt], Bh[1][kt], C1, 0, 0, 0);
            C0 = __builtin_amdgcn_mfma_f32_16x16x32_bf16(Al[kt], Bh[0][kt], C0, 0, 0, 0);
            C1 = __builtin_amdgcn_mfma_f32_16x16x32_bf16(Al[kt], Bh[1][kt], C1, 0, 0, 0);
            C0 = __builtin_amdgcn_mfma_f32_16x16x32_bf16(Ah[kt], Bl[0][kt], C0, 0, 0, 0);
            C1 = __builtin_amdgcn_mfma_f32_16x16x32_bf16(Ah[kt], Bl[1][kt], C1, 0, 0, 0);
        }

        // ---- epilogue: softthr, split hi/lo, write next buffer ----
        const int nxt = cur ^ 1;
        #pragma unroll
        for (int n2 = 0; n2 < 2; ++n2) {
            const int col = (wv * 2 + n2) * 16 + l15;
            const f32x4 C = n2 ? C1 : C0;
            #pragma unroll
            for (int q = 0; q < 4; ++q) {
                const int row = lg * 4 + q;
                const float s = C[q];
                float mag = fabsf(s) - th;
                mag = mag > 0.f ? mag : 0.f;
                const float r = (s >= 0.f) ? mag : -mag;
                const unsigned short hb = f2bf(r);
                const unsigned short lb = f2bf(r - bf2f(hb));
                const unsigned off =
                    (unsigned)((row * KPAD + col) * 2) ^ (unsigned)((row & 7) << 4);
                *(unsigned short*)((char*)dh[nxt] + off) = hb;
                *(unsigned short*)((char*)dl[nxt] + off) = lb;
            }
        }
        __syncthreads();   // single barrier: next iter's writes hit old cur,
        cur ^= 1;          // whose reads all completed before this barrier
    }

    // ---- output (hi+lo recombine; repr err ~2^-18, irrelevant) ----
    for (int idx = t; idx < ROWS * N_DIM; idx += NTHREADS) {
        const int row = idx / N_DIM;
        const int col = idx - row * N_DIM;
        const unsigned off =
            (unsigned)((row * KPAD + col) * 2) ^ (unsigned)((row & 7) << 4);
        const float v = bf2f(*(const unsigned short*)((const char*)dh[cur] + off))
                      + bf2f(*(const unsigned short*)((const char*)dl[cur] + off));
        out[(size_t)(row0 + row) * N_DIM + col] = v;
    }
}

extern "C" void kernel_launch(void* const* d_in, const int* in_sizes, int n_in,
                              void* d_out, int out_size, void* d_ws, size_t ws_size,
                              hipStream_t stream) {
    const float* y       = (const float*)d_in[0];
    const float* S       = (const float*)d_in[1];
    const float* W       = (const float*)d_in[2];
    const float* thr     = (const float*)d_in[3];
    const int*   numIter = (const int*)d_in[4];
    float* out = (float*)d_out;

    const int Brows = in_sizes[0] / M_DIM;   // 4096
    const int nblk  = Brows / ROWS;          // 256 blocks = 1/CU
    ista_mfma<<<nblk, NTHREADS, 0, stream>>>(y, S, W, thr, numIter, out);
}